// Round 3
// baseline (169.083 us; speedup 1.0000x reference)
//
#include <hip/hip_runtime.h>
#include <hip/hip_bf16.h>

#define NB 16
#define NS 2048
#define NE 256
#define NOUT 256
#define NTILE 16        // 2048/128 tiles per dim
#define TRI 136         // 16*17/2 triangle tiles per batch
#define NCHUNK 544      // 16*136/4 : 4 tiles per block
#define NIT 16          // 4 tiles * 4 kt

typedef __attribute__((ext_vector_type(4))) float f32x4;
typedef __attribute__((ext_vector_type(8))) short s16x8;
typedef __attribute__((ext_vector_type(4))) short s16x4;
typedef unsigned int u32;

__device__ __forceinline__ short bf16rn(float f) {
  unsigned u = __builtin_bit_cast(unsigned, f);
  u += 0x7FFFu + ((u >> 16) & 1u);
  return (short)(u >> 16);
}
__device__ __forceinline__ float bf16f(short s) {
  unsigned u = ((unsigned)(unsigned short)s) << 16;
  return __builtin_bit_cast(float, u);
}
__device__ __forceinline__ void gld_lds16(const void* g, void* l) {
  __builtin_amdgcn_global_load_lds(
      (const __attribute__((address_space(1))) u32*)g,
      (__attribute__((address_space(3))) u32*)l, 16, 0, 0);
}

// decode triangle tile index T in [0,136) -> (by, bx)
__device__ __forceinline__ void tri_decode(int T, int& by, int& bx) {
  float f = sqrtf((float)(1089 - 8 * T));
  int b = (int)((33.0f - f) * 0.5f);
  if (b * (33 - b) / 2 > T) --b;
  else if ((b + 1) * (32 - b) / 2 <= T) ++b;
  by = b;
  bx = b + (T - b * (33 - b) / 2);
}

// stage one 128x64(bf16) A tile + B tile into lds buffer (linear dest,
// inverse-swizzled source so swizzled ds_read matches)
__device__ __forceinline__ void stage(char* ldsbase, const short* xbf, int bb,
                                      int rowbase, int colbase, int kt, int wid,
                                      int lane) {
  const char* xb = (const char*)(xbf + (size_t)bb * NS * NE);
  const int boff = ((lane & 7) * 16) ^ (((lane >> 3) & 7) << 4);
  const char* gA =
      xb + (size_t)(rowbase + wid * 32 + (lane >> 3)) * 512 + boff + kt * 128;
  const char* gB =
      xb + (size_t)(colbase + wid * 32 + (lane >> 3)) * 512 + boff + kt * 128;
  char* lA = ldsbase + wid * 32 * 128 + lane * 16;
  char* lB = ldsbase + 16384 + wid * 32 * 128 + lane * 16;
#pragma unroll
  for (int i = 0; i < 4; ++i) {
    gld_lds16(gA + i * 4096, lA + i * 1024);
    gld_lds16(gB + i * 4096, lB + i * 1024);
  }
}

// one BK=64 MFMA step from a staged buffer
__device__ __forceinline__ void compute64(const char* bufA, const char* bufB,
                                          int wr, int wc, int lrow, int lq,
                                          f32x4 acc[4][4]) {
#pragma unroll
  for (int kk = 0; kk < 2; ++kk) {
    s16x8 af[4], bfv[4];
#pragma unroll
    for (int m = 0; m < 4; ++m) {
      int r = wr * 64 + m * 16 + lrow;
      int byt = r * 128 + (((kk * 64) + lq * 16) ^ ((r & 7) << 4));
      af[m] = *(const s16x8*)(bufA + byt);
    }
#pragma unroll
    for (int n = 0; n < 4; ++n) {
      int r = wc * 64 + n * 16 + lrow;
      int byt = r * 128 + (((kk * 64) + lq * 16) ^ ((r & 7) << 4));
      bfv[n] = *(const s16x8*)(bufB + byt);
    }
#pragma unroll
    for (int m = 0; m < 4; ++m)
#pragma unroll
      for (int n = 0; n < 4; ++n)
        acc[m][n] = __builtin_amdgcn_mfma_f32_16x16x32_bf16(af[m], bfv[n],
                                                            acc[m][n], 0, 0, 0);
  }
}

// ---------- prep: x f32 -> xbf bf16 + sq ----------
__global__ __launch_bounds__(256) void prep_kernel(const float* __restrict__ x,
                                                   short* __restrict__ xbf,
                                                   float* __restrict__ sq) {
  int row = blockIdx.x * 4 + (threadIdx.x >> 6);
  int lane = threadIdx.x & 63;
  f32x4 v = *(const f32x4*)(x + (size_t)row * NE + lane * 4);
  s16x4 p;
  p[0] = bf16rn(v.x); p[1] = bf16rn(v.y); p[2] = bf16rn(v.z); p[3] = bf16rn(v.w);
  *(s16x4*)(xbf + (size_t)row * NE + lane * 4) = p;
  float s = v.x * v.x + v.y * v.y + v.z * v.z + v.w * v.w;
#pragma unroll
  for (int off = 32; off; off >>= 1) s += __shfl_xor(s, off);
  if (lane == 0) sq[row] = s;
}

// ---------- gram1: persistent 4-tile blocks, dbuf pipeline ----------
__global__ __launch_bounds__(256, 2) void gram1(
    const short* __restrict__ xbf, const float* __restrict__ sqg,
    const float* __restrict__ alpha_p, float* __restrict__ rws,
    int* __restrict__ flags) {
  __shared__ char lds[65536];  // 2 x (A 16KB + B 16KB)

  const int tid = threadIdx.x;
  const int lane = tid & 63;
  const int wid = tid >> 6;
  const int wr = wid >> 1, wc = wid & 1;
  const int lrow = lane & 15, lq = lane >> 4;
  const float alpha = alpha_p[0];
  const float nal = -alpha;
  const float thresh = 17.328680f / alpha;  // 25 ln2 / alpha

  // XCD-chunked: 544 = 8 * 68
  const int chunk = (blockIdx.x & 7) * 68 + (blockIdx.x >> 3);
  const int Gbase = chunk * 4;

  f32x4 acc[4][4];
#pragma unroll
  for (int m = 0; m < 4; ++m)
#pragma unroll
    for (int n = 0; n < 4; ++n) acc[m][n] = (f32x4){0.f, 0.f, 0.f, 0.f};

  {
    int g = Gbase, bb = g / 136, by, bx;
    tri_decode(g - bb * 136, by, bx);
    stage(lds, xbf, bb, by * 128, bx * 128, 0, wid, lane);
  }
  __syncthreads();

#pragma unroll 1
  for (int it = 0; it < NIT; ++it) {
    const int cur = it & 1;
    if (it + 1 < NIT) {
      int g2 = Gbase + ((it + 1) >> 2);
      int bb2 = g2 / 136, by2, bx2;
      tri_decode(g2 - bb2 * 136, by2, bx2);
      stage(lds + (cur ^ 1) * 32768, xbf, bb2, by2 * 128, bx2 * 128,
            (it + 1) & 3, wid, lane);
    }
    compute64(lds + cur * 32768, lds + cur * 32768 + 16384, wr, wc, lrow, lq,
              acc);

    if ((it & 3) == 3) {
      // epilogue for tile (it>>2)
      int g = Gbase + (it >> 2);
      int bb = g / 136, by, bx;
      tri_decode(g - bb * 136, by, bx);
      const int rowbase = by * 128, colbase = bx * 128;
      const float* sqrow = sqg + bb * NS + rowbase;
      const float* sqcol = sqg + bb * NS + colbase;

      float ssq[4][4], sqtl[4];
#pragma unroll
      for (int m = 0; m < 4; ++m)
#pragma unroll
        for (int j = 0; j < 4; ++j) ssq[m][j] = sqrow[wr * 64 + m * 16 + lq * 4 + j];
#pragma unroll
      for (int n = 0; n < 4; ++n) sqtl[n] = sqcol[wc * 64 + n * 16 + lrow];

      float mind2 = 3.4e38f;
#pragma unroll
      for (int m = 0; m < 4; ++m)
#pragma unroll
        for (int n = 0; n < 4; ++n)
#pragma unroll
          for (int j = 0; j < 4; ++j)
            mind2 = fminf(mind2, fmaf(-2.f, acc[m][n][j], ssq[m][j] + sqtl[n]));
      const bool skip = __all(mind2 > thresh);

      if (skip) {
        if (lrow == 0) {
#pragma unroll
          for (int m = 0; m < 4; ++m)
#pragma unroll
            for (int j = 0; j < 4; ++j)
              atomicAdd(&rws[bb * NS + rowbase + wr * 64 + m * 16 + lq * 4 + j],
                        64.0f);
        }
        if (by != bx && lq == 0) {
#pragma unroll
          for (int n = 0; n < 4; ++n)
            atomicAdd(&rws[bb * NS + colbase + wc * 64 + n * 16 + lrow], 64.0f);
        }
      } else {
        if (lane == 0) {
          atomicOr(&flags[bb * 256 + by * 16 + bx], 1);
          if (by != bx) atomicOr(&flags[bb * 256 + bx * 16 + by], 1);
        }
        float csum[4] = {0.f, 0.f, 0.f, 0.f};
#pragma unroll
        for (int m = 0; m < 4; ++m) {
#pragma unroll
          for (int j = 0; j < 4; ++j) {
            float rsum = 0.f;
#pragma unroll
            for (int n = 0; n < 4; ++n) {
              float d2 = fmaxf(fmaf(-2.f, acc[m][n][j], ssq[m][j] + sqtl[n]), 0.f);
              float w = __expf(__expf(nal * d2));
              rsum += w;
              csum[n] += w;
            }
            rsum += __shfl_xor(rsum, 1);
            rsum += __shfl_xor(rsum, 2);
            rsum += __shfl_xor(rsum, 4);
            rsum += __shfl_xor(rsum, 8);
            if (lrow == 0)
              atomicAdd(&rws[bb * NS + rowbase + wr * 64 + m * 16 + lq * 4 + j],
                        rsum);
          }
        }
        if (by != bx) {
#pragma unroll
          for (int n = 0; n < 4; ++n) {
            float v = csum[n];
            v += __shfl_xor(v, 16);
            v += __shfl_xor(v, 32);
            if (lq == 0)
              atomicAdd(&rws[bb * NS + colbase + wc * 64 + n * 16 + lrow], v);
          }
        }
      }
      // reset accumulator for next tile
#pragma unroll
      for (int m = 0; m < 4; ++m)
#pragma unroll
        for (int n = 0; n < 4; ++n) acc[m][n] = (f32x4){0.f, 0.f, 0.f, 0.f};
    }
    __syncthreads();
  }
}

// ---------- rinv + analytic cws baseline (one block per batch) ----------
__global__ __launch_bounds__(256) void rinv_cinit(const float* __restrict__ rws,
                                                  const int* __restrict__ flags,
                                                  float* __restrict__ rinv_g,
                                                  float* __restrict__ cws) {
  __shared__ float rb[16];
  const int b = blockIdx.x, tid = threadIdx.x;
  const int lane = tid & 63;
  if (tid < 16) rb[tid] = 0.f;
  __syncthreads();
#pragma unroll
  for (int k = 0; k < 8; ++k) {
    int r = tid + k * 256;
    float inv = 1.0f / rws[b * NS + r];
    rinv_g[b * NS + r] = inv;
    float s = inv;
#pragma unroll
    for (int off = 32; off; off >>= 1) s += __shfl_xor(s, off);
    if (lane == 0) atomicAdd(&rb[r >> 7], s);
  }
  __syncthreads();
#pragma unroll
  for (int k = 0; k < 8; ++k) {
    int t = tid + k * 256;
    int bx = t >> 7;
    float base = 0.f;
#pragma unroll
    for (int by = 0; by < 16; ++by)
      if (flags[b * 256 + by * 16 + bx] == 0) base += rb[by];
    cws[b * NS + t] = base;  // store (replaces memset of cws)
  }
}

// ---------- gram2: flagged tiles only, dbuf pipeline ----------
__global__ __launch_bounds__(256, 2) void gram2(
    const short* __restrict__ xbf, const float* __restrict__ sqg,
    const float* __restrict__ alpha_p, const float* __restrict__ rinv_g,
    const int* __restrict__ flags, float* __restrict__ cws) {
  __shared__ char lds[65536];

  const int bid = blockIdx.x;  // 4096 = 8 * 512
  const int nbid = (bid & 7) * 512 + (bid >> 3);
  const int bb = nbid >> 8;
  const int rr = nbid & 255;
  const int by = rr >> 4, bx = rr & 15;
  if (flags[bb * 256 + by * 16 + bx] == 0) return;

  const int rowbase = by * 128, colbase = bx * 128;
  const int tid = threadIdx.x;
  const int lane = tid & 63;
  const int wid = tid >> 6;
  const int wr = wid >> 1, wc = wid & 1;
  const int lrow = lane & 15, lq = lane >> 4;
  const float alpha = alpha_p[0];
  const float nal = -alpha;

  f32x4 acc[4][4];
#pragma unroll
  for (int m = 0; m < 4; ++m)
#pragma unroll
    for (int n = 0; n < 4; ++n) acc[m][n] = (f32x4){0.f, 0.f, 0.f, 0.f};

  stage(lds, xbf, bb, rowbase, colbase, 0, wid, lane);
  __syncthreads();
#pragma unroll 1
  for (int it = 0; it < 4; ++it) {
    const int cur = it & 1;
    if (it + 1 < 4)
      stage(lds + (cur ^ 1) * 32768, xbf, bb, rowbase, colbase, it + 1, wid, lane);
    compute64(lds + cur * 32768, lds + cur * 32768 + 16384, wr, wc, lrow, lq,
              acc);
    __syncthreads();
  }

  const float* sqrow = sqg + bb * NS + rowbase;
  const float* sqcol = sqg + bb * NS + colbase;
  const float* rirow = rinv_g + bb * NS + rowbase;
  float csum[4] = {0.f, 0.f, 0.f, 0.f};
#pragma unroll
  for (int m = 0; m < 4; ++m) {
#pragma unroll
    for (int j = 0; j < 4; ++j) {
      int rl = wr * 64 + m * 16 + lq * 4 + j;
      float ssq = sqrow[rl];
      float ri = rirow[rl];
#pragma unroll
      for (int n = 0; n < 4; ++n) {
        float d2 = fmaxf(fmaf(-2.f, acc[m][n][j], ssq + sqcol[wc * 64 + n * 16 + lrow]), 0.f);
        float w0 = __expf(nal * d2);
        csum[n] = fmaf(__expf(w0), ri, csum[n]);
      }
    }
  }
#pragma unroll
  for (int n = 0; n < 4; ++n) {
    float v = csum[n];
    v += __shfl_xor(v, 16);
    v += __shfl_xor(v, 32);
    if (lq == 0) atomicAdd(&cws[bb * NS + colbase + wc * 64 + n * 16 + lrow], v);
  }
}

// ---------- pooled[b,e] = (1/S) sum_t c[b,t] x[b,t,e] (vectorized) ----------
__global__ __launch_bounds__(256) void pooled_kernel(const short* __restrict__ xbf,
                                                     const float* __restrict__ cws,
                                                     float* __restrict__ pooled) {
  __shared__ float red[8 * 256];
  const int b = blockIdx.y;
  const int t0 = blockIdx.x * 128;
  const short* xb = xbf + ((size_t)b * NS + t0) * NE;
  const float* cb = cws + b * NS + t0;
  const int g = threadIdx.x >> 5;
  const int e8 = (threadIdx.x & 31) * 8;
  float acc[8] = {0.f, 0.f, 0.f, 0.f, 0.f, 0.f, 0.f, 0.f};
#pragma unroll 4
  for (int t = g; t < 128; t += 8) {
    float cv = cb[t];
    s16x8 v = *(const s16x8*)(xb + (size_t)t * NE + e8);
#pragma unroll
    for (int j = 0; j < 8; ++j) acc[j] = fmaf(cv, bf16f(v[j]), acc[j]);
  }
#pragma unroll
  for (int j = 0; j < 8; ++j) red[g * 256 + e8 + j] = acc[j];
  __syncthreads();
  float s = 0.f;
#pragma unroll
  for (int g2 = 0; g2 < 8; ++g2) s += red[g2 * 256 + threadIdx.x];
  atomicAdd(&pooled[b * NE + threadIdx.x], s * (1.0f / NS));
}

// ---------- out[b,o] = pooled[b,:] . W[o,:] + bias[o] ----------
__global__ __launch_bounds__(256) void out_kernel(const float* __restrict__ pooled,
                                                  const float* __restrict__ W,
                                                  const float* __restrict__ bias,
                                                  float* __restrict__ out) {
  __shared__ float pl[NE];
  int b = blockIdx.x, o = threadIdx.x;
  pl[o] = pooled[b * NE + o];
  __syncthreads();
  const f32x4* wr4 = (const f32x4*)(W + (size_t)o * NE);
  float acc = bias[o];
#pragma unroll 8
  for (int e = 0; e < 64; ++e) {
    f32x4 w4 = wr4[e];
    acc += pl[e * 4 + 0] * w4.x + pl[e * 4 + 1] * w4.y + pl[e * 4 + 2] * w4.z +
           pl[e * 4 + 3] * w4.w;
  }
  out[b * NOUT + o] = acc;
}

extern "C" void kernel_launch(void* const* d_in, const int* in_sizes, int n_in,
                              void* d_out, int out_size, void* d_ws, size_t ws_size,
                              hipStream_t stream) {
  const float* x = (const float*)d_in[0];
  const float* alpha = (const float*)d_in[1];
  const float* W = (const float*)d_in[2];
  const float* bias = (const float*)d_in[3];
  float* out = (float*)d_out;

  float* rws = (float*)d_ws;                 // NB*NS
  float* pooled = rws + NB * NS;             // NB*NE
  int* flags = (int*)(pooled + NB * NE);     // NB*256
  float* cws = (float*)(flags + NB * 256);   // NB*NS (stored by rinv_cinit)
  float* sq = cws + NB * NS;                 // NB*NS
  float* rinv_g = sq + NB * NS;              // NB*NS
  short* xbf = (short*)(rinv_g + NB * NS);   // NB*NS*NE bf16

  // zero rws, pooled, flags (contiguous)
  hipMemsetAsync(rws, 0, (size_t)(NB * NS + NB * NE + NB * 256) * sizeof(float),
                 stream);

  prep_kernel<<<NB * NS / 4, 256, 0, stream>>>(x, xbf, sq);
  gram1<<<NCHUNK, 256, 0, stream>>>(xbf, sq, alpha, rws, flags);
  rinv_cinit<<<NB, 256, 0, stream>>>(rws, flags, rinv_g, cws);
  gram2<<<NB * 256, 256, 0, stream>>>(xbf, sq, alpha, rinv_g, flags, cws);
  pooled_kernel<<<dim3(16, NB), 256, 0, stream>>>(xbf, cws, pooled);
  out_kernel<<<NB, 256, 0, stream>>>(pooled, W, bias, out);
}